// Round 6
// baseline (2258.147 us; speedup 1.0000x reference)
//
#include <hip/hip_runtime.h>

typedef __attribute__((ext_vector_type(8))) short short8;
typedef __attribute__((ext_vector_type(4))) float floatx4;
typedef unsigned int u32;
typedef unsigned short u16;

// ---------- helpers ----------
__device__ __forceinline__ u16 f2bf(float f) {
  u32 u = __float_as_uint(f);
  u += 0x7FFFu + ((u >> 16) & 1u);   // RNE
  return (u16)(u >> 16);
}

typedef const __attribute__((address_space(1))) u32* gp1_t;
typedef __attribute__((address_space(3))) u32* lp3_t;

__device__ __forceinline__ void gld16(const void* g, void* l) {
  // async global -> LDS, 16B per lane; LDS dest is wave-uniform base + lane*16
  __builtin_amdgcn_global_load_lds((gp1_t)g, (lp3_t)l, 16, 0, 0);
}

// ---------- kernel 1: fused prep = dequant (first ndq blocks) + xconv ----------
// dequant: int4 -> Wt[n][k] bf16 (round-0 scatter-store version: aux timing
// history shows it beats the LDS-transpose variant).  xconv: x f32 -> bf16,
// plain thread-per-float4 (grid-stride version regressed).  Fused into one
// launch so the two independent jobs run concurrently.
__global__ __launch_bounds__(256) void prep(
    const float* __restrict__ x, u16* __restrict__ xb, long long n4,
    const int* __restrict__ qw, const int* __restrict__ qz,
    const int* __restrict__ qs, const float* __restrict__ qsz,
    const float* __restrict__ qss, const int* __restrict__ gidx,
    u16* __restrict__ Wt, int IN, int OUT, int ndq) {
  const int bid = blockIdx.x;
  if (bid < ndq) {
    // ---- dequant block ----
    const int nbx = OUT >> 6;
    const int n = (bid % nbx) * 64 + (threadIdx.x & 63);
    const int w = threadIdx.x >> 6;                  // 0..3
    const int k0 = (bid / nbx) * 128 + w * 32;       // one 32-wide group
    const int g = gidx[k0];                          // uniform across wave
    const int kk0 = k0 >> 3;                         // 4 packed rows
    const int zq = ((qz[(size_t)g * (OUT >> 3) + (n >> 3)] >> (4 * (n & 7))) & 15) + 1;
    const float sc = ((float)qs[(size_t)g * OUT + n] - qsz[g]) * qss[g];
    u16* dst = Wt + (size_t)n * IN + k0;
#pragma unroll
    for (int j = 0; j < 4; ++j) {
      const int w32 = qw[(size_t)(kk0 + j) * OUT + n];   // coalesced across lanes
      u16 o[8];
#pragma unroll
      for (int s = 0; s < 8; ++s)
        o[s] = f2bf((float)(((w32 >> (4 * s)) & 15) - zq) * sc);
      uint4 pk;
      pk.x = (u32)o[0] | ((u32)o[1] << 16);
      pk.y = (u32)o[2] | ((u32)o[3] << 16);
      pk.z = (u32)o[4] | ((u32)o[5] << 16);
      pk.w = (u32)o[6] | ((u32)o[7] << 16);
      *(uint4*)(dst + j * 8) = pk;
    }
  } else {
    // ---- xconv block ----
    long long i = (long long)(bid - ndq) * 256 + threadIdx.x;
    if (i >= n4) return;
    float4 v = ((const float4*)x)[i];
    ushort4 o;
    o.x = f2bf(v.x); o.y = f2bf(v.y); o.z = f2bf(v.z); o.w = f2bf(v.w);
    ((ushort4*)xb)[i] = o;
  }
}

// ---------- kernel 2: 256x256 bf16 GEMM, ONE barrier per K-tile ----------
// C = A(MxK)*Bt(NxK)^T.  8 waves (2m x 4n), per-wave 128x64 C, 16x16x32
// MFMA, BK=64, buf b = tile parity.  Evolution of round-5 (2 barriers/tile,
// 242us, MfmaUtil 51.6): the mid barrier is removed via a depth-1 stage
// rotation -- during tile t (buf b) each wave stages BOTH A[b^1] and
// B[b^1] <- tile t+1.
// Correctness (exact, not timing-based): each wave's tile-t ds_reads are
// consumed by its own MFMAs (compiler lgkmcnt) before it reaches tile t+1's
// entry barrier, so that barrier is a completion fence for all waves' LDS
// reads of buf b^1's previous contents (last read in tile t-1).  The
// overwriting gld16 are issued only after the barrier.  vmcnt(0) at entry
// drains this wave's 8 loads issued a full tile (~4000cyc) earlier -> HBM
// latency fully hidden (the m97 drain hurt because loads issued LATE).
// Per tile: vmcnt(0); barrier; read bF(8)+aL(8); stage A+B (8 gld16);
// MFMA q0; read aH(8); MFMA q1,q2,q3 (setprio-wrapped, 16 each).
// Swizzle: row stride 64 bf16 = 128B = 8 granules; store granule c at
// c^(row&7) (pre-swizzled global source; gld_lds writes linearly), undone
// on ds_read -> measured 0 bank conflicts (rounds 1/5).
__global__ __launch_bounds__(512, 2) void gemm256(const u16* __restrict__ A,
                                                  const u16* __restrict__ Bt,
                                                  float* __restrict__ C,
                                                  int M, int N, int K) {
  __shared__ u16 As[2][16384];
  __shared__ u16 Bs[2][16384];
  const int tid = threadIdx.x;
  const int lane = tid & 63;
  const int wave = tid >> 6;          // 0..7
  const int wm = wave >> 2;           // 0..1
  const int wn = wave & 3;            // 0..3
  const int lr = lane & 15, quad = lane >> 4;

  // bijective XCD-aware block swizzle (m204 form)
  const int nbx = N >> 8;
  const int nwg = gridDim.x;
  const int bid = blockIdx.x;
  const int q8 = nwg >> 3, r8 = nwg & 7;
  const int xcd = bid & 7, loc = bid >> 3;
  const int swz = (xcd < r8 ? xcd * (q8 + 1) : r8 * (q8 + 1) + (xcd - r8) * q8) + loc;
  const int n0 = (swz % nbx) << 8;
  const int m0 = (swz / nbx) << 8;

  floatx4 acc[8][4] = {};

  // ---- staging source (per-thread; carries the store swizzle) ----
  // one gld16 covers 64 rows x 64 k: wave w rows w*8+(lane>>3), granule
  // lane&7, source granule ^= row&7
  const int srow = lane >> 3;
  const int sch8 = ((lane & 7) ^ (srow & 7)) * 8;
  const u16* aS = A + (size_t)(m0 + wave * 8 + srow) * K + sch8;
  const u16* bS = Bt + (size_t)(n0 + wave * 8 + srow) * K + sch8;

#define STAGE_A(buf, kt) do {                                                 \
    _Pragma("unroll") for (int h_ = 0; h_ < 2; ++h_) {                        \
      const u16* s_ = aS + (size_t)h_ * 128 * K + (size_t)(kt) * 64;          \
      u16* d_ = &As[buf][(h_ * 128 + wave * 8) * 64];                         \
      gld16(s_, d_); gld16(s_ + (size_t)64 * K, d_ + 4096);                   \
    } } while (0)
#define STAGE_B(buf, kt) do {                                                 \
    _Pragma("unroll") for (int h_ = 0; h_ < 2; ++h_) {                        \
      const u16* s_ = bS + (size_t)h_ * 128 * K + (size_t)(kt) * 64;          \
      u16* d_ = &Bs[buf][(h_ * 128 + wave * 8) * 64];                         \
      gld16(s_, d_); gld16(s_ + (size_t)64 * K, d_ + 4096);                   \
    } } while (0)

  // ---- fragment read bases (swizzle undone; row&7 == lr&7) ----
  const int rl = lr & 7;
  const int cs0 = ((0 * 4 + quad) ^ rl) * 8;   // ksub 0
  const int cs1 = ((1 * 4 + quad) ^ rl) * 8;   // ksub 1
  const u16* a0rd = &As[0][(wm * 128 + lr) * 64];
  const u16* a1rd = &As[1][(wm * 128 + lr) * 64];
  const u16* b0rd = &Bs[0][(wn * 64 + lr) * 64];
  const u16* b1rd = &Bs[1][(wn * 64 + lr) * 64];

#define MFMA16(JB, AARR)                                                      \
    __builtin_amdgcn_s_setprio(1);                                            \
    _Pragma("unroll") for (int s = 0; s < 2; ++s)                             \
      _Pragma("unroll") for (int j = 0; j < 2; ++j)                           \
        _Pragma("unroll") for (int nt = 0; nt < 4; ++nt)                      \
          acc[(JB) + j][nt] = __builtin_amdgcn_mfma_f32_16x16x32_bf16(        \
              AARR[((JB) & 2) + j][s], bF[nt][s], acc[(JB) + j][nt], 0, 0, 0);\
    __builtin_amdgcn_s_setprio(0);

#define TILE(ARD, BRD, STG) do {                                              \
    asm volatile("s_waitcnt vmcnt(0)" ::: "memory");                          \
    __builtin_amdgcn_s_barrier();                                             \
    short8 bF[4][2], aL[4][2], aH[4][2];                                      \
    _Pragma("unroll") for (int nt = 0; nt < 4; ++nt) {                        \
      bF[nt][0] = *(const short8*)((BRD) + nt * 1024 + cs0);                  \
      bF[nt][1] = *(const short8*)((BRD) + nt * 1024 + cs1);                  \
    }                                                                         \
    _Pragma("unroll") for (int j = 0; j < 4; ++j) {                           \
      aL[j][0] = *(const short8*)((ARD) + j * 1024 + cs0);                    \
      aL[j][1] = *(const short8*)((ARD) + j * 1024 + cs1);                    \
    }                                                                         \
    STG;                                                                      \
    MFMA16(0, aL)                                                             \
    _Pragma("unroll") for (int j = 0; j < 4; ++j) {                           \
      aH[j][0] = *(const short8*)((ARD) + (4 + j) * 1024 + cs0);              \
      aH[j][1] = *(const short8*)((ARD) + (4 + j) * 1024 + cs1);              \
    }                                                                         \
    MFMA16(2, aL)                                                             \
    MFMA16(4, aH)                                                             \
    MFMA16(6, aH)                                                             \
  } while (0)

  // ---- prologue: buf0 <- tile0 ----
  STAGE_A(0, 0);
  STAGE_B(0, 0);

  const int NI = K >> 7;                  // iters of 2 K-tiles
  for (int i = 0; i < NI; ++i) {
    const int kt = 2 * i;
    TILE(a0rd, b0rd, { STAGE_A(1, kt + 1); STAGE_B(1, kt + 1); });
    if (i < NI - 1) {
      TILE(a1rd, b1rd, { STAGE_A(0, kt + 2); STAGE_B(0, kt + 2); });
    } else {
      TILE(a1rd, b1rd, (void)0);
    }
  }
#undef TILE
#undef MFMA16
#undef STAGE_A
#undef STAGE_B

  // ---- epilogue: C/D layout col=lane&15, row=quad*4+reg ----
#pragma unroll
  for (int mt = 0; mt < 8; ++mt)
#pragma unroll
    for (int nt = 0; nt < 4; ++nt)
#pragma unroll
      for (int r = 0; r < 4; ++r) {
        int row = m0 + wm * 128 + mt * 16 + quad * 4 + r;
        int col = n0 + wn * 64 + nt * 16 + lr;
        C[(size_t)row * N + col] = acc[mt][nt][r];
      }
}

// ---------- kernel 2b (fallback): 128x128 bf16 GEMM ----------
__global__ __launch_bounds__(256) void gemm(const u16* __restrict__ A,
                                            const u16* __restrict__ Bt,
                                            float* __restrict__ C,
                                            int M, int N, int K) {
  __shared__ u16 As[128 * 64];
  __shared__ u16 Bs[128 * 64];
  const int tid = threadIdx.x;
  const int lane = tid & 63;
  const int wave = tid >> 6;
  const int wm = wave & 1, wn = wave >> 1;
  const int lr = lane & 15, quad = lane >> 4;
  const int m0 = blockIdx.y * 128, n0 = blockIdx.x * 128;

  floatx4 acc[4][4] = {};

  const int srowB = (lane >> 3);
  const int schunk = (lane & 7) ^ srowB;
  const int rowA0 = wave * 32;
  const u16* aSrc = A + (size_t)(m0 + rowA0 + srowB) * K + schunk * 8;
  const u16* bSrc = Bt + (size_t)(n0 + rowA0 + srowB) * K + schunk * 8;
  u16* aDst = &As[rowA0 * 64];
  u16* bDst = &Bs[rowA0 * 64];
  const size_t rstep = (size_t)8 * K;

  const int rx = lr & 7;

  for (int k0 = 0; k0 < K; k0 += 64) {
    __syncthreads();
#pragma unroll
    for (int c = 0; c < 4; ++c) {
      gld16(aSrc + c * rstep + k0, aDst + c * 8 * 64);
      gld16(bSrc + c * rstep + k0, bDst + c * 8 * 64);
    }
    __syncthreads();

#pragma unroll
    for (int h = 0; h < 2; ++h) {
      short8 aF[4], bF[4];
      const int rc = ((quad + 4 * h) ^ rx) * 8;
#pragma unroll
      for (int t = 0; t < 4; ++t) {
        aF[t] = *(const short8*)&As[(wm * 64 + t * 16 + lr) * 64 + rc];
        bF[t] = *(const short8*)&Bs[(wn * 64 + t * 16 + lr) * 64 + rc];
      }
#pragma unroll
      for (int mt = 0; mt < 4; ++mt)
#pragma unroll
        for (int nt = 0; nt < 4; ++nt)
          acc[mt][nt] = __builtin_amdgcn_mfma_f32_16x16x32_bf16(
              aF[mt], bF[nt], acc[mt][nt], 0, 0, 0);
    }
  }

#pragma unroll
  for (int mt = 0; mt < 4; ++mt)
#pragma unroll
    for (int nt = 0; nt < 4; ++nt)
#pragma unroll
      for (int r = 0; r < 4; ++r) {
        int row = m0 + wm * 64 + mt * 16 + quad * 4 + r;
        int col = n0 + wn * 64 + nt * 16 + lr;
        C[(size_t)row * N + col] = acc[mt][nt][r];
      }
}

// ---------- fallback: naive dequant-on-the-fly ----------
__global__ void naive(const float* __restrict__ x, const int* __restrict__ qw,
                      const int* __restrict__ qz, const int* __restrict__ qs,
                      const float* __restrict__ qsz, const float* __restrict__ qss,
                      const int* __restrict__ gidx, float* __restrict__ out,
                      int M, int N, int K) {
  int n = blockIdx.x * 64 + (threadIdx.x & 63);
  int m = blockIdx.y * 4 + (threadIdx.x >> 6);
  if (n >= N || m >= M) return;
  float acc = 0.f;
  for (int kk = 0; kk < K / 8; ++kk) {
    int w32 = qw[(size_t)kk * N + n];
#pragma unroll
    for (int s = 0; s < 8; ++s) {
      int k = kk * 8 + s;
      int g = gidx[k];
      int zq = ((qz[(size_t)g * (N >> 3) + (n >> 3)] >> (4 * (n & 7))) & 15) + 1;
      float sc = ((float)qs[(size_t)g * N + n] - qsz[g]) * qss[g];
      acc += x[(size_t)m * K + k] * ((float)((w32 >> (4 * s)) & 15) - (float)zq) * sc;
    }
  }
  out[(size_t)m * N + n] = acc;
}

extern "C" void kernel_launch(void* const* d_in, const int* in_sizes, int n_in,
                              void* d_out, int out_size, void* d_ws, size_t ws_size,
                              hipStream_t stream) {
  const float* x = (const float*)d_in[0];
  const int* qw = (const int*)d_in[1];
  const int* qz = (const int*)d_in[2];
  const int* qs = (const int*)d_in[3];
  const float* qsz = (const float*)d_in[4];
  const float* qss = (const float*)d_in[5];
  const int* gidx = (const int*)d_in[6];
  const int IN = in_sizes[6];                                   // 4096
  const int OUT = (int)(((long long)in_sizes[1] * 8) / IN);     // 4096
  const int M = in_sizes[0] / IN;                               // 8192
  float* out = (float*)d_out;

  size_t bytesW = (size_t)IN * OUT * 2;
  size_t bytesX = (size_t)M * IN * 2;
  bool haveWs = (ws_size >= bytesW + bytesX);
  bool fast256 = haveWs && (M % 256 == 0) && (OUT % 256 == 0) &&
                 (IN % 256 == 0) && (IN >= 256);
  bool fast128 = haveWs && (M % 128 == 0) && (OUT % 128 == 0) && (IN % 128 == 0);

  if (fast256 || fast128) {
    u16* Wt = (u16*)d_ws;
    u16* Xb = (u16*)((char*)d_ws + bytesW);
    long long n4 = (long long)M * IN / 4;
    int ndq = (OUT / 64) * (IN / 128);
    long long nxc = (n4 + 255) / 256;
    prep<<<(int)(ndq + nxc), 256, 0, stream>>>(x, Xb, n4, qw, qz, qs, qsz, qss,
                                               gidx, Wt, IN, OUT, ndq);
    if (fast256) {
      int nblk = (M / 256) * (OUT / 256);
      gemm256<<<dim3(nblk), 512, 0, stream>>>(Xb, Wt, out, M, OUT, IN);
    } else {
      gemm<<<dim3(OUT / 128, M / 128), 256, 0, stream>>>(Xb, Wt, out, M, OUT, IN);
    }
  } else {
    naive<<<dim3((OUT + 63) / 64, (M + 3) / 4), 256, 0, stream>>>(
        x, qw, qz, qs, qsz, qss, gidx, out, M, OUT, IN);
  }
}

// Round 7
// 464.450 us; speedup vs baseline: 4.8620x; 4.8620x over previous
//
#include <hip/hip_runtime.h>

typedef __attribute__((ext_vector_type(8))) short short8;
typedef __attribute__((ext_vector_type(4))) float floatx4;
typedef unsigned int u32;
typedef unsigned short u16;

// ---------- helpers ----------
__device__ __forceinline__ u16 f2bf(float f) {
  u32 u = __float_as_uint(f);
  u += 0x7FFFu + ((u >> 16) & 1u);   // RNE
  return (u16)(u >> 16);
}

typedef const __attribute__((address_space(1))) u32* gp1_t;
typedef __attribute__((address_space(3))) u32* lp3_t;

__device__ __forceinline__ void gld16(const void* g, void* l) {
  // async global -> LDS, 16B per lane; LDS dest is wave-uniform base + lane*16
  __builtin_amdgcn_global_load_lds((gp1_t)g, (lp3_t)l, 16, 0, 0);
}

// ---------- kernel 1: fused prep = dequant (first ndq blocks) + xconv ----------
// Kept from round 6 (aux gap 233 -> 185 us).  dequant is the round-0
// scatter-store version; xconv plain thread-per-float4.
__global__ __launch_bounds__(256) void prep(
    const float* __restrict__ x, u16* __restrict__ xb, long long n4,
    const int* __restrict__ qw, const int* __restrict__ qz,
    const int* __restrict__ qs, const float* __restrict__ qsz,
    const float* __restrict__ qss, const int* __restrict__ gidx,
    u16* __restrict__ Wt, int IN, int OUT, int ndq) {
  const int bid = blockIdx.x;
  if (bid < ndq) {
    // ---- dequant block ----
    const int nbx = OUT >> 6;
    const int n = (bid % nbx) * 64 + (threadIdx.x & 63);
    const int w = threadIdx.x >> 6;                  // 0..3
    const int k0 = (bid / nbx) * 128 + w * 32;       // one 32-wide group
    const int g = gidx[k0];                          // uniform across wave
    const int kk0 = k0 >> 3;                         // 4 packed rows
    const int zq = ((qz[(size_t)g * (OUT >> 3) + (n >> 3)] >> (4 * (n & 7))) & 15) + 1;
    const float sc = ((float)qs[(size_t)g * OUT + n] - qsz[g]) * qss[g];
    u16* dst = Wt + (size_t)n * IN + k0;
#pragma unroll
    for (int j = 0; j < 4; ++j) {
      const int w32 = qw[(size_t)(kk0 + j) * OUT + n];   // coalesced across lanes
      u16 o[8];
#pragma unroll
      for (int s = 0; s < 8; ++s)
        o[s] = f2bf((float)(((w32 >> (4 * s)) & 15) - zq) * sc);
      uint4 pk;
      pk.x = (u32)o[0] | ((u32)o[1] << 16);
      pk.y = (u32)o[2] | ((u32)o[3] << 16);
      pk.z = (u32)o[4] | ((u32)o[5] << 16);
      pk.w = (u32)o[6] | ((u32)o[7] << 16);
      *(uint4*)(dst + j * 8) = pk;
    }
  } else {
    // ---- xconv block ----
    long long i = (long long)(bid - ndq) * 256 + threadIdx.x;
    if (i >= n4) return;
    float4 v = ((const float4*)x)[i];
    ushort4 o;
    o.x = f2bf(v.x); o.y = f2bf(v.y); o.z = f2bf(v.z); o.w = f2bf(v.w);
    ((ushort4*)xb)[i] = o;
  }
}

// ---------- kernel 2: 256x256 bf16 GEMM, 2 barriers per K-tile ----------
// EXACT round-5 structure (verified 242us, MfmaUtil 51.6%, 0 conflicts,
// VGPR 128, no spill).  Round-6 lesson: removing the mid barrier + merging
// the two stage clusters pushes the live set (bF+aL+aH+8 stage addrs) past
// the 128 arch-VGPR budget (acc holds 128 AGPRs; launch_bounds(512,2) caps
// unified at 256) -> scratch spill, 7.6GB of writes, 8.5x slowdown.  The
// two-barrier TILE is what keeps the allocator under budget; DO NOT merge.
//   vmcnt(4); entry barrier;
//   issue bF(8) + aL(8) ds_read_b128; issue stage A(b^1)<-t+1 (4 gld16);
//   MFMA q0 (16, setprio);
//   issue aH(8) ds_read; MFMA q1 (16);
//   mid barrier;                       // orders all waves' bF reads first
//   issue stage B(b)<-t+2 (4 gld16);
//   MFMA q2 (16); MFMA q3 (16);
// Race-freedom: A(b^1) last read pre-entry-barrier (prev tile); B(b) read
// only at tile entry, ordered by mid barrier; vmcnt(4) at entry = all but
// the newest stage (B<-t+2, 4 loads) landed => A(t),B(t) complete.
// Swizzle: row stride 64 bf16 = 128B = 8 granules; store granule c at
// c^(row&7) (pre-swizzled global source; gld_lds writes linearly), undone
// on ds_read -> measured 0 bank conflicts.
#define VM4 asm volatile("s_waitcnt vmcnt(4)" ::: "memory")
#define VM0 asm volatile("s_waitcnt vmcnt(0)" ::: "memory")

__global__ __launch_bounds__(512, 2) void gemm256(const u16* __restrict__ A,
                                                  const u16* __restrict__ Bt,
                                                  float* __restrict__ C,
                                                  int M, int N, int K) {
  __shared__ u16 As[2][16384];
  __shared__ u16 Bs[2][16384];
  const int tid = threadIdx.x;
  const int lane = tid & 63;
  const int wave = tid >> 6;          // 0..7
  const int wm = wave >> 2;           // 0..1
  const int wn = wave & 3;            // 0..3
  const int lr = lane & 15, quad = lane >> 4;

  // bijective XCD-aware block swizzle (m204 form)
  const int nbx = N >> 8;
  const int nwg = gridDim.x;
  const int bid = blockIdx.x;
  const int q8 = nwg >> 3, r8 = nwg & 7;
  const int xcd = bid & 7, loc = bid >> 3;
  const int swz = (xcd < r8 ? xcd * (q8 + 1) : r8 * (q8 + 1) + (xcd - r8) * q8) + loc;
  const int n0 = (swz % nbx) << 8;
  const int m0 = (swz / nbx) << 8;

  floatx4 acc[8][4] = {};

  // ---- staging source (per-thread; carries the store swizzle) ----
  // one gld16 covers 64 rows x 64 k: wave w rows w*8+(lane>>3), granule
  // lane&7, source granule ^= row&7
  const int srow = lane >> 3;
  const int sch8 = ((lane & 7) ^ (srow & 7)) * 8;
  const u16* aS = A + (size_t)(m0 + wave * 8 + srow) * K + sch8;
  const u16* bS = Bt + (size_t)(n0 + wave * 8 + srow) * K + sch8;

#define STAGE_A(buf, kt) do {                                                 \
    _Pragma("unroll") for (int h_ = 0; h_ < 2; ++h_) {                        \
      const u16* s_ = aS + (size_t)h_ * 128 * K + (size_t)(kt) * 64;          \
      u16* d_ = &As[buf][(h_ * 128 + wave * 8) * 64];                         \
      gld16(s_, d_); gld16(s_ + (size_t)64 * K, d_ + 4096);                   \
    } } while (0)
#define STAGE_B(buf, kt) do {                                                 \
    _Pragma("unroll") for (int h_ = 0; h_ < 2; ++h_) {                        \
      const u16* s_ = bS + (size_t)h_ * 128 * K + (size_t)(kt) * 64;          \
      u16* d_ = &Bs[buf][(h_ * 128 + wave * 8) * 64];                         \
      gld16(s_, d_); gld16(s_ + (size_t)64 * K, d_ + 4096);                   \
    } } while (0)

  // ---- fragment read bases (swizzle undone; row&7 == lr&7) ----
  const int rl = lr & 7;
  const int cs0 = ((0 * 4 + quad) ^ rl) * 8;   // ksub 0
  const int cs1 = ((1 * 4 + quad) ^ rl) * 8;   // ksub 1
  const u16* a0rd = &As[0][(wm * 128 + lr) * 64];
  const u16* a1rd = &As[1][(wm * 128 + lr) * 64];
  const u16* b0rd = &Bs[0][(wn * 64 + lr) * 64];
  const u16* b1rd = &Bs[1][(wn * 64 + lr) * 64];

#define MFMA16(JB, AARR)                                                      \
    __builtin_amdgcn_s_setprio(1);                                            \
    _Pragma("unroll") for (int s = 0; s < 2; ++s)                             \
      _Pragma("unroll") for (int j = 0; j < 2; ++j)                           \
        _Pragma("unroll") for (int nt = 0; nt < 4; ++nt)                      \
          acc[(JB) + j][nt] = __builtin_amdgcn_mfma_f32_16x16x32_bf16(        \
              AARR[((JB) & 2) + j][s], bF[nt][s], acc[(JB) + j][nt], 0, 0, 0);\
    __builtin_amdgcn_s_setprio(0);

#define TILE(ARD, BRD, STGA, STGB, VMW) do {                                  \
    VMW;                                                                      \
    __builtin_amdgcn_s_barrier();                                             \
    short8 bF[4][2], aL[4][2], aH[4][2];                                      \
    _Pragma("unroll") for (int nt = 0; nt < 4; ++nt) {                        \
      bF[nt][0] = *(const short8*)((BRD) + nt * 1024 + cs0);                  \
      bF[nt][1] = *(const short8*)((BRD) + nt * 1024 + cs1);                  \
    }                                                                         \
    _Pragma("unroll") for (int j = 0; j < 4; ++j) {                           \
      aL[j][0] = *(const short8*)((ARD) + j * 1024 + cs0);                    \
      aL[j][1] = *(const short8*)((ARD) + j * 1024 + cs1);                    \
    }                                                                         \
    STGA;                                                                     \
    MFMA16(0, aL)                                                             \
    _Pragma("unroll") for (int j = 0; j < 4; ++j) {                           \
      aH[j][0] = *(const short8*)((ARD) + (4 + j) * 1024 + cs0);              \
      aH[j][1] = *(const short8*)((ARD) + (4 + j) * 1024 + cs1);              \
    }                                                                         \
    MFMA16(2, aL)                                                             \
    __builtin_amdgcn_s_barrier();   /* mid: B-reads before B-overwrite */     \
    STGB;                                                                     \
    MFMA16(4, aH)                                                             \
    MFMA16(6, aH)                                                             \
  } while (0)

  // ---- prologue: B0, A0 (buf0, tile0), B1 (buf1, tile1) ----
  STAGE_B(0, 0);
  STAGE_A(0, 0);
  STAGE_B(1, 1);

  const int NI = K >> 7;                  // iters of 2 K-tiles
  for (int i = 0; i < NI - 1; ++i) {
    const int kt = 2 * i;
    TILE(a0rd, b0rd, { STAGE_A(1, kt + 1); }, { STAGE_B(0, kt + 2); }, VM4);
    TILE(a1rd, b1rd, { STAGE_A(0, kt + 2); }, { STAGE_B(1, kt + 3); }, VM4);
  }
  // last pair: tiles 2*NI-2 (buf0), 2*NI-1 (buf1)
  TILE(a0rd, b0rd, { STAGE_A(1, 2 * NI - 1); }, (void)0, VM4);
  TILE(a1rd, b1rd, (void)0, (void)0, VM0);
#undef TILE
#undef MFMA16
#undef STAGE_A
#undef STAGE_B

  // ---- epilogue: C/D layout col=lane&15, row=quad*4+reg ----
#pragma unroll
  for (int mt = 0; mt < 8; ++mt)
#pragma unroll
    for (int nt = 0; nt < 4; ++nt)
#pragma unroll
      for (int r = 0; r < 4; ++r) {
        int row = m0 + wm * 128 + mt * 16 + quad * 4 + r;
        int col = n0 + wn * 64 + nt * 16 + lr;
        C[(size_t)row * N + col] = acc[mt][nt][r];
      }
}

// ---------- kernel 2b (fallback): 128x128 bf16 GEMM ----------
__global__ __launch_bounds__(256) void gemm(const u16* __restrict__ A,
                                            const u16* __restrict__ Bt,
                                            float* __restrict__ C,
                                            int M, int N, int K) {
  __shared__ u16 As[128 * 64];
  __shared__ u16 Bs[128 * 64];
  const int tid = threadIdx.x;
  const int lane = tid & 63;
  const int wave = tid >> 6;
  const int wm = wave & 1, wn = wave >> 1;
  const int lr = lane & 15, quad = lane >> 4;
  const int m0 = blockIdx.y * 128, n0 = blockIdx.x * 128;

  floatx4 acc[4][4] = {};

  const int srowB = (lane >> 3);
  const int schunk = (lane & 7) ^ srowB;
  const int rowA0 = wave * 32;
  const u16* aSrc = A + (size_t)(m0 + rowA0 + srowB) * K + schunk * 8;
  const u16* bSrc = Bt + (size_t)(n0 + rowA0 + srowB) * K + schunk * 8;
  u16* aDst = &As[rowA0 * 64];
  u16* bDst = &Bs[rowA0 * 64];
  const size_t rstep = (size_t)8 * K;

  const int rx = lr & 7;

  for (int k0 = 0; k0 < K; k0 += 64) {
    __syncthreads();
#pragma unroll
    for (int c = 0; c < 4; ++c) {
      gld16(aSrc + c * rstep + k0, aDst + c * 8 * 64);
      gld16(bSrc + c * rstep + k0, bDst + c * 8 * 64);
    }
    __syncthreads();

#pragma unroll
    for (int h = 0; h < 2; ++h) {
      short8 aF[4], bF[4];
      const int rc = ((quad + 4 * h) ^ rx) * 8;
#pragma unroll
      for (int t = 0; t < 4; ++t) {
        aF[t] = *(const short8*)&As[(wm * 64 + t * 16 + lr) * 64 + rc];
        bF[t] = *(const short8*)&Bs[(wn * 64 + t * 16 + lr) * 64 + rc];
      }
#pragma unroll
      for (int mt = 0; mt < 4; ++mt)
#pragma unroll
        for (int nt = 0; nt < 4; ++nt)
          acc[mt][nt] = __builtin_amdgcn_mfma_f32_16x16x32_bf16(
              aF[mt], bF[nt], acc[mt][nt], 0, 0, 0);
    }
  }

#pragma unroll
  for (int mt = 0; mt < 4; ++mt)
#pragma unroll
    for (int nt = 0; nt < 4; ++nt)
#pragma unroll
      for (int r = 0; r < 4; ++r) {
        int row = m0 + wm * 64 + mt * 16 + quad * 4 + r;
        int col = n0 + wn * 64 + nt * 16 + lr;
        C[(size_t)row * N + col] = acc[mt][nt][r];
      }
}

// ---------- fallback: naive dequant-on-the-fly ----------
__global__ void naive(const float* __restrict__ x, const int* __restrict__ qw,
                      const int* __restrict__ qz, const int* __restrict__ qs,
                      const float* __restrict__ qsz, const float* __restrict__ qss,
                      const int* __restrict__ gidx, float* __restrict__ out,
                      int M, int N, int K) {
  int n = blockIdx.x * 64 + (threadIdx.x & 63);
  int m = blockIdx.y * 4 + (threadIdx.x >> 6);
  if (n >= N || m >= M) return;
  float acc = 0.f;
  for (int kk = 0; kk < K / 8; ++kk) {
    int w32 = qw[(size_t)kk * N + n];
#pragma unroll
    for (int s = 0; s < 8; ++s) {
      int k = kk * 8 + s;
      int g = gidx[k];
      int zq = ((qz[(size_t)g * (N >> 3) + (n >> 3)] >> (4 * (n & 7))) & 15) + 1;
      float sc = ((float)qs[(size_t)g * N + n] - qsz[g]) * qss[g];
      acc += x[(size_t)m * K + k] * ((float)((w32 >> (4 * s)) & 15) - (float)zq) * sc;
    }
  }
  out[(size_t)m * N + n] = acc;
}

extern "C" void kernel_launch(void* const* d_in, const int* in_sizes, int n_in,
                              void* d_out, int out_size, void* d_ws, size_t ws_size,
                              hipStream_t stream) {
  const float* x = (const float*)d_in[0];
  const int* qw = (const int*)d_in[1];
  const int* qz = (const int*)d_in[2];
  const int* qs = (const int*)d_in[3];
  const float* qsz = (const float*)d_in[4];
  const float* qss = (const float*)d_in[5];
  const int* gidx = (const int*)d_in[6];
  const int IN = in_sizes[6];                                   // 4096
  const int OUT = (int)(((long long)in_sizes[1] * 8) / IN);     // 4096
  const int M = in_sizes[0] / IN;                               // 8192
  float* out = (float*)d_out;

  size_t bytesW = (size_t)IN * OUT * 2;
  size_t bytesX = (size_t)M * IN * 2;
  bool haveWs = (ws_size >= bytesW + bytesX);
  bool fast256 = haveWs && (M % 256 == 0) && (OUT % 256 == 0) &&
                 (IN % 256 == 0) && (IN >= 256);
  bool fast128 = haveWs && (M % 128 == 0) && (OUT % 128 == 0) && (IN % 128 == 0);

  if (fast256 || fast128) {
    u16* Wt = (u16*)d_ws;
    u16* Xb = (u16*)((char*)d_ws + bytesW);
    long long n4 = (long long)M * IN / 4;
    int ndq = (OUT / 64) * (IN / 128);
    long long nxc = (n4 + 255) / 256;
    prep<<<(int)(ndq + nxc), 256, 0, stream>>>(x, Xb, n4, qw, qz, qs, qsz, qss,
                                               gidx, Wt, IN, OUT, ndq);
    if (fast256) {
      int nblk = (M / 256) * (OUT / 256);
      gemm256<<<dim3(nblk), 512, 0, stream>>>(Xb, Wt, out, M, OUT, IN);
    } else {
      gemm<<<dim3(OUT / 128, M / 128), 256, 0, stream>>>(Xb, Wt, out, M, OUT, IN);
    }
  } else {
    naive<<<dim3((OUT + 63) / 64, (M + 3) / 4), 256, 0, stream>>>(
        x, qw, qz, qs, qsz, qss, gidx, out, M, OUT, IN);
  }
}